// Round 4
// baseline (5559.086 us; speedup 1.0000x reference)
//
#include <hip/hip_runtime.h>

// SiameseClassifier: twin LSTM (shared weights) over T=128 steps, B=128 each,
// E=H=1024, V=32000. out[b] = exp(-L1(h_a[b], h_b[b])).
//
// R4: persistent cooperative kernel.
//  - One kernel runs all 128 steps; 256 blocks (1/CU) x 512 thr, co-resident
//    via hipLaunchCooperativeKernel; custom 2-level device-scope barrier.
//  - 8 waves = kq(4 K-quarters) x fp(2 gate-pairs). Each wave holds its
//    32KB W-slice in 128 VGPRs (s16x8 brs[2][16]) for ALL steps (loaded once).
//  - c and bias live in registers across steps (fixed thread<->cell map).
//  - A=[x|h] staged per step in XOR-swizzled LDS (bank-floor verified maps).
//  - Gate partials combined via Gs4 LDS, fused cell update, h ping-pong.

typedef unsigned short u16;
typedef __attribute__((ext_vector_type(8))) unsigned short u16x8;
typedef __attribute__((ext_vector_type(8))) short s16x8;
typedef __attribute__((ext_vector_type(4))) float f32x4;

__device__ __forceinline__ u16 f2bf(float f) {
  unsigned int u = __builtin_bit_cast(unsigned int, f);
  u += 0x7fffu + ((u >> 16) & 1u);   // RNE
  return (u16)(u >> 16);
}
__device__ __forceinline__ float bf2f(u16 x) {
  unsigned int u = ((unsigned int)x) << 16;
  return __builtin_bit_cast(float, u);
}

// ---------------- prep: weights into fragment order (same layout as R3) ----
// Wf idx8 = ((nh*4 + f)*64 + kcg)*64 + lane ; elems 8 per idx8
//   element: W[f*1024 + nh*16 + (lane&15)][kcg*32 + (lane>>4)*8 + j]
__global__ __launch_bounds__(256) void prep_wf_kernel(const float* __restrict__ w_ih,
                                                      const float* __restrict__ w_hh,
                                                      u16* __restrict__ Wf) {
  unsigned idx = blockIdx.x * 256u + threadIdx.x;          // 0..1048575
  unsigned l = idx & 63u;
  unsigned kcg = (idx >> 6) & 63u;
  unsigned f = (idx >> 12) & 3u;
  unsigned nh = idx >> 14;
  unsigned r = f * 1024u + nh * 16u + (l & 15u);
  unsigned k0 = kcg * 32u + ((l >> 4) << 3);
  const float* src = (k0 < 1024u) ? (w_ih + (size_t)r * 1024u + k0)
                                  : (w_hh + (size_t)r * 1024u + (k0 - 1024u));
  float4 v0 = *(const float4*)src;
  float4 v1 = *(const float4*)(src + 4);
  u16x8 o;
  o[0] = f2bf(v0.x); o[1] = f2bf(v0.y); o[2] = f2bf(v0.z); o[3] = f2bf(v0.w);
  o[4] = f2bf(v1.x); o[5] = f2bf(v1.y); o[6] = f2bf(v1.z); o[7] = f2bf(v1.w);
  *(u16x8*)(Wf + (size_t)idx * 8u) = o;
}

// ---------------- prep: h0 -> hb0 (bf16), gather x0, zero barrier ----------
__global__ __launch_bounds__(256) void prep_state_kernel(
    const float* __restrict__ h0a, const float* __restrict__ h0b,
    const int* __restrict__ batch_a, const int* __restrict__ batch_b,
    const float* __restrict__ emb,
    u16* __restrict__ hb0, u16* __restrict__ xb0, unsigned* __restrict__ bar) {
  unsigned i = blockIdx.x * 256u + threadIdx.x;
  unsigned r = i >> 10;
  unsigned k = i & 1023u;
  hb0[i] = f2bf((r < 128u) ? h0a[i] : h0b[i - 131072u]);
  int token = (r < 128u) ? batch_a[r] : batch_b[r - 128u];
  xb0[i] = f2bf(emb[(size_t)token * 1024u + k]);
  if (i < 64u) bar[i] = 0u;
}

// ---------------- persistent LSTM ----------------
// grid 256 = m(4) x nh(64). block 512 = 8 waves = kq(4) x fp(2).
// bar layout: bar[g*4], g=0..7 group counters (16B apart); bar[32]=bar2; bar[33]=gen
__global__ __launch_bounds__(512, 2) void lstm_persist_kernel(
    const int* __restrict__ batch_a, const int* __restrict__ batch_b,
    const float* __restrict__ emb, const u16* __restrict__ Wf,
    const float* __restrict__ b_ih, const float* __restrict__ b_hh,
    const float* __restrict__ c0a, const float* __restrict__ c0b,
    u16* __restrict__ xb0, u16* __restrict__ xb1,
    u16* __restrict__ hb0, u16* __restrict__ hb1,
    unsigned* __restrict__ bar) {
  __shared__ u16 As[4][64][128];      // 64 KB, XOR-swizzled rows (256 B)
  __shared__ float Gs4[4][64][66];    // 67.6 KB, kq partial gates

  const int tid = threadIdx.x;
  const int lane = tid & 63;
  const int w = tid >> 6;
  const int kq = w >> 1, fp = w & 1;
  const int m = blockIdx.x >> 6;
  const int nh = blockIdx.x & 63;

  // ---- persistent B fragments: 32 KB/wave in 128 VGPRs, loaded once ----
  s16x8 brs[2][16];
#pragma unroll
  for (int fc = 0; fc < 2; ++fc) {
    const u16* base = Wf + ((size_t)((nh * 4 + (fp * 2 + fc)) * 64 + kq * 16) << 9)
                         + lane * 8;
#pragma unroll
    for (int kc = 0; kc < 16; ++kc)
      brs[fc][kc] = *(const s16x8*)(base + ((size_t)kc << 9));
  }

  // ---- persistent cell state (c) + bias in registers ----
  const int crow = tid >> 3;            // 0..63
  const int u0 = (tid & 7) << 1;        // unit pair
  const int R2 = m * 64 + crow;
  const int gj = nh * 16 + u0;
  float bias_r[4][2];
#pragma unroll
  for (int f = 0; f < 4; ++f) {
    bias_r[f][0] = b_ih[f * 1024 + gj] + b_hh[f * 1024 + gj];
    bias_r[f][1] = b_ih[f * 1024 + gj + 1] + b_hh[f * 1024 + gj + 1];
  }
  float creg[2];
  creg[0] = (R2 < 128) ? c0a[R2 * 1024 + gj] : c0b[(R2 - 128) * 1024 + gj];
  creg[1] = (R2 < 128) ? c0a[R2 * 1024 + gj + 1] : c0b[(R2 - 128) * 1024 + gj + 1];

  // ---- staging thread map: 4 kq-windows x 64 rows x 128 elems ----
  const int kqw = tid >> 7;             // which window this thread stages
  const int trow = (tid & 127) >> 1;    // 0..63
  const int tcol = (tid & 1) << 6;      // 0 or 64 (elems)
  const int swz = (trow & 7) << 4;
  const int grow = m * 64 + trow;
  char* dstrow = (char*)&As[kqw][trow][0];

  // ---- fragment read ids ----
  const int fr = lane & 15;
  const int fkb = (lane >> 4) << 4;     // bytes
  const int rswz = (fr & 7) << 4;
  const char* asKq = (const char*)&As[kq][0][0];

  const unsigned grp = blockIdx.x & 7;
  f32x4 acc[4][2];

  for (int t = 0; t < 128; ++t) {
    const u16* x_in = (t & 1) ? xb1 : xb0;
    u16* x_nx = (t & 1) ? xb0 : xb1;
    const u16* h_in = (t & 1) ? hb1 : hb0;
    u16* h_out = (t & 1) ? hb0 : hb1;

#pragma unroll
    for (int a_ = 0; a_ < 4; ++a_)
#pragma unroll
      for (int b_ = 0; b_ < 2; ++b_) acc[a_][b_] = (f32x4){0.f, 0.f, 0.f, 0.f};

    const u16* srcbase = (kqw < 2 ? x_in : h_in)
                         + (size_t)grow * 1024 + ((kqw * 512) & 1023) + tcol;

#pragma unroll
    for (int it = 0; it < 4; ++it) {
      __syncthreads();                  // prev iter's frag reads done
      const u16* s = srcbase + it * 128;
      u16x8 r0 = *(const u16x8*)(s);
      u16x8 r1 = *(const u16x8*)(s + 8);
      u16x8 r2 = *(const u16x8*)(s + 16);
      u16x8 r3 = *(const u16x8*)(s + 24);
      *(u16x8*)(dstrow + ((tcol * 2 + 0) ^ swz)) = r0;
      *(u16x8*)(dstrow + ((tcol * 2 + 16) ^ swz)) = r1;
      *(u16x8*)(dstrow + ((tcol * 2 + 32) ^ swz)) = r2;
      *(u16x8*)(dstrow + ((tcol * 2 + 48) ^ swz)) = r3;
      u16x8 r4 = *(const u16x8*)(s + 32);
      u16x8 r5 = *(const u16x8*)(s + 40);
      u16x8 r6 = *(const u16x8*)(s + 48);
      u16x8 r7 = *(const u16x8*)(s + 56);
      *(u16x8*)(dstrow + ((tcol * 2 + 64) ^ swz)) = r4;
      *(u16x8*)(dstrow + ((tcol * 2 + 80) ^ swz)) = r5;
      *(u16x8*)(dstrow + ((tcol * 2 + 96) ^ swz)) = r6;
      *(u16x8*)(dstrow + ((tcol * 2 + 112) ^ swz)) = r7;
      __syncthreads();
#pragma unroll
      for (int kcl = 0; kcl < 4; ++kcl) {
        const int kb = (kcl * 64 + fkb) ^ rswz;
        s16x8 af0 = *(const s16x8*)(asKq + (0 * 16 + fr) * 256 + kb);
        s16x8 af1 = *(const s16x8*)(asKq + (1 * 16 + fr) * 256 + kb);
        s16x8 af2 = *(const s16x8*)(asKq + (2 * 16 + fr) * 256 + kb);
        s16x8 af3 = *(const s16x8*)(asKq + (3 * 16 + fr) * 256 + kb);
        const int kc = it * 4 + kcl;
        acc[0][0] = __builtin_amdgcn_mfma_f32_16x16x32_bf16(af0, brs[0][kc], acc[0][0], 0, 0, 0);
        acc[1][0] = __builtin_amdgcn_mfma_f32_16x16x32_bf16(af1, brs[0][kc], acc[1][0], 0, 0, 0);
        acc[2][0] = __builtin_amdgcn_mfma_f32_16x16x32_bf16(af2, brs[0][kc], acc[2][0], 0, 0, 0);
        acc[3][0] = __builtin_amdgcn_mfma_f32_16x16x32_bf16(af3, brs[0][kc], acc[3][0], 0, 0, 0);
        acc[0][1] = __builtin_amdgcn_mfma_f32_16x16x32_bf16(af0, brs[1][kc], acc[0][1], 0, 0, 0);
        acc[1][1] = __builtin_amdgcn_mfma_f32_16x16x32_bf16(af1, brs[1][kc], acc[1][1], 0, 0, 0);
        acc[2][1] = __builtin_amdgcn_mfma_f32_16x16x32_bf16(af2, brs[1][kc], acc[2][1], 0, 0, 0);
        acc[3][1] = __builtin_amdgcn_mfma_f32_16x16x32_bf16(af3, brs[1][kc], acc[3][1], 0, 0, 0);
      }
    }

    // ---- write kq-partial gates to LDS ----
#pragma unroll
    for (int frg = 0; frg < 4; ++frg)
#pragma unroll
      for (int fc = 0; fc < 2; ++fc)
#pragma unroll
        for (int r_ = 0; r_ < 4; ++r_)
          Gs4[kq][frg * 16 + ((lane >> 4) << 2) + r_][fp * 32 + fc * 16 + (lane & 15)] =
              acc[frg][fc][r_];
    __syncthreads();

    // ---- fused cell update (c,bias in regs), h write ----
    {
      float hv[2];
#pragma unroll
      for (int uu = 0; uu < 2; ++uu) {
        int cix = u0 + uu;
        float iv = Gs4[0][crow][cix]      + Gs4[1][crow][cix]      + Gs4[2][crow][cix]      + Gs4[3][crow][cix]      + bias_r[0][uu];
        float fv = Gs4[0][crow][16 + cix] + Gs4[1][crow][16 + cix] + Gs4[2][crow][16 + cix] + Gs4[3][crow][16 + cix] + bias_r[1][uu];
        float gv = Gs4[0][crow][32 + cix] + Gs4[1][crow][32 + cix] + Gs4[2][crow][32 + cix] + Gs4[3][crow][32 + cix] + bias_r[2][uu];
        float ov = Gs4[0][crow][48 + cix] + Gs4[1][crow][48 + cix] + Gs4[2][crow][48 + cix] + Gs4[3][crow][48 + cix] + bias_r[3][uu];
        float si = 1.f / (1.f + __expf(-iv));
        float sf = 1.f / (1.f + __expf(-fv));
        float so = 1.f / (1.f + __expf(-ov));
        float cn = sf * creg[uu] + si * tanhf(gv);
        creg[uu] = cn;
        hv[uu] = so * tanhf(cn);
      }
      unsigned pk = (unsigned)f2bf(hv[0]) | ((unsigned)f2bf(hv[1]) << 16);
      *(unsigned*)(h_out + (size_t)R2 * 1024 + gj) = pk;
    }

    // ---- pre-gather x_{t+1}: block r stages emb row -> x_nx ----
    if (t + 1 < 128 && tid < 128) {
      int r = blockIdx.x;
      int token = (r < 128) ? batch_a[(t + 1) * 128 + r]
                            : batch_b[(t + 1) * 128 + (r - 128)];
      const float* es = emb + (size_t)token * 1024 + tid * 8;
      float4 v0 = *(const float4*)es;
      float4 v1 = *(const float4*)(es + 4);
      u16x8 o;
      o[0] = f2bf(v0.x); o[1] = f2bf(v0.y); o[2] = f2bf(v0.z); o[3] = f2bf(v0.w);
      o[4] = f2bf(v1.x); o[5] = f2bf(v1.y); o[6] = f2bf(v1.z); o[7] = f2bf(v1.w);
      *(u16x8*)(x_nx + (size_t)r * 1024 + tid * 8) = o;
    }

    // ---- grid barrier (2-level, monotonic generations) ----
    __syncthreads();
    if (tid == 0) {
      __threadfence();                                   // release (device scope)
      unsigned a = __hip_atomic_fetch_add(&bar[grp * 4], 1u, __ATOMIC_ACQ_REL,
                                          __HIP_MEMORY_SCOPE_AGENT);
      if ((a & 31u) == 31u) {                            // last of 32 in group
        unsigned g = __hip_atomic_fetch_add(&bar[32], 1u, __ATOMIC_ACQ_REL,
                                            __HIP_MEMORY_SCOPE_AGENT);
        if ((g & 7u) == 7u)                              // last group -> release
          __hip_atomic_fetch_add(&bar[33], 1u, __ATOMIC_ACQ_REL,
                                 __HIP_MEMORY_SCOPE_AGENT);
      }
      while (__hip_atomic_load(&bar[33], __ATOMIC_ACQUIRE,
                               __HIP_MEMORY_SCOPE_AGENT) < (unsigned)(t + 1)) {
        __builtin_amdgcn_s_sleep(2);
      }
      __threadfence();                                   // acquire (invalidate)
    }
    __syncthreads();
  }
}

// ---------------- finalize ----------------
__global__ __launch_bounds__(256) void finalize_kernel(const u16* __restrict__ h,
                                                       float* __restrict__ out) {
  int b = blockIdx.x;
  int tid = threadIdx.x;
  const u16* ha = h + (size_t)b * 1024;
  const u16* hb = h + (size_t)(b + 128) * 1024;
  float s = 0.f;
  for (int j = tid; j < 1024; j += 256) s += fabsf(bf2f(ha[j]) - bf2f(hb[j]));
  __shared__ float red[256];
  red[tid] = s;
  __syncthreads();
  for (int off = 128; off > 0; off >>= 1) {
    if (tid < off) red[tid] += red[tid + off];
    __syncthreads();
  }
  if (tid == 0) out[b] = expf(-red[0]);
}

extern "C" void kernel_launch(void* const* d_in, const int* in_sizes, int n_in,
                              void* d_out, int out_size, void* d_ws, size_t ws_size,
                              hipStream_t stream) {
  const int* batch_a = (const int*)d_in[0];
  const int* batch_b = (const int*)d_in[1];
  const float* h0_a = (const float*)d_in[2];
  const float* c0_a = (const float*)d_in[3];
  const float* h0_b = (const float*)d_in[4];
  const float* c0_b = (const float*)d_in[5];
  const float* emb  = (const float*)d_in[6];
  const float* w_ih = (const float*)d_in[7];
  const float* w_hh = (const float*)d_in[8];
  const float* b_ih = (const float*)d_in[9];
  const float* b_hh = (const float*)d_in[10];

  char* ws = (char*)d_ws;
  u16* Wf  = (u16*)(ws);                       // 16,777,216 B
  u16* xb0 = (u16*)(ws + 16777216);            //    524,288 B
  u16* xb1 = (u16*)(ws + 17301504);            //    524,288 B
  u16* hb0 = (u16*)(ws + 17825792);            //    524,288 B
  u16* hb1 = (u16*)(ws + 18350080);            //    524,288 B
  unsigned* bar = (unsigned*)(ws + 18874368);  //        256 B

  prep_wf_kernel<<<4096, 256, 0, stream>>>(w_ih, w_hh, Wf);
  prep_state_kernel<<<1024, 256, 0, stream>>>(h0_a, h0_b, batch_a, batch_b, emb,
                                              hb0, xb0, bar);

  void* args[] = {(void*)&batch_a, (void*)&batch_b, (void*)&emb, (void*)&Wf,
                  (void*)&b_ih, (void*)&b_hh, (void*)&c0_a, (void*)&c0_b,
                  (void*)&xb0, (void*)&xb1, (void*)&hb0, (void*)&hb1,
                  (void*)&bar};
  hipLaunchCooperativeKernel((void*)lstm_persist_kernel, dim3(256), dim3(512),
                             args, 0, stream);

  finalize_kernel<<<128, 256, 0, stream>>>(hb0, (float*)d_out);
}

// Round 5
// 5327.561 us; speedup vs baseline: 1.0435x; 1.0435x over previous
//
#include <hip/hip_runtime.h>

// SiameseClassifier: twin LSTM (shared weights) over T=128 steps, B=128 each,
// E=H=1024, V=32000. out[b] = exp(-L1(h_a[b], h_b[b])).
//
// R5: persistent cooperative kernel, R3 per-step dataflow (no W-in-VGPR).
//  - One kernel, 128 steps, 256 blocks x 512 thr (1 block/CU).
//  - Per step: A=[x|h] staged in XOR-swizzled double-buffered LDS (bank-floor
//    maps, verified in R3); B-frags streamed from fragment-ordered Wf (L2)
//    with double-buffered register prefetch. No W residency -> no spills.
//  - c state + bias in registers across all 128 steps.
//  - 4 INDEPENDENT per-m-group barriers (64 blocks each): the 4 row-groups
//    share no data (h/x rows and c are disjoint per m).
//  - x_{t+1} emb-gather loads issued at step top (latency hidden under GEMM).

typedef unsigned short u16;
typedef __attribute__((ext_vector_type(8))) unsigned short u16x8;
typedef __attribute__((ext_vector_type(8))) short s16x8;
typedef __attribute__((ext_vector_type(4))) float f32x4;

__device__ __forceinline__ u16 f2bf(float f) {
  unsigned int u = __builtin_bit_cast(unsigned int, f);
  u += 0x7fffu + ((u >> 16) & 1u);   // RNE
  return (u16)(u >> 16);
}
__device__ __forceinline__ float bf2f(u16 x) {
  unsigned int u = ((unsigned int)x) << 16;
  return __builtin_bit_cast(float, u);
}

// ---------------- prep: weights into fragment order ----------------
// Wf idx8 = ((nh*4 + f)*64 + kcg)*64 + lane ; 8 elems per idx8
//   element: W[f*1024 + nh*16 + (lane&15)][kcg*32 + (lane>>4)*8 + j]
__global__ __launch_bounds__(256) void prep_wf_kernel(const float* __restrict__ w_ih,
                                                      const float* __restrict__ w_hh,
                                                      u16* __restrict__ Wf) {
  unsigned idx = blockIdx.x * 256u + threadIdx.x;          // 0..1048575
  unsigned l = idx & 63u;
  unsigned kcg = (idx >> 6) & 63u;
  unsigned f = (idx >> 12) & 3u;
  unsigned nh = idx >> 14;
  unsigned r = f * 1024u + nh * 16u + (l & 15u);
  unsigned k0 = kcg * 32u + ((l >> 4) << 3);
  const float* src = (k0 < 1024u) ? (w_ih + (size_t)r * 1024u + k0)
                                  : (w_hh + (size_t)r * 1024u + (k0 - 1024u));
  float4 v0 = *(const float4*)src;
  float4 v1 = *(const float4*)(src + 4);
  u16x8 o;
  o[0] = f2bf(v0.x); o[1] = f2bf(v0.y); o[2] = f2bf(v0.z); o[3] = f2bf(v0.w);
  o[4] = f2bf(v1.x); o[5] = f2bf(v1.y); o[6] = f2bf(v1.z); o[7] = f2bf(v1.w);
  *(u16x8*)(Wf + (size_t)idx * 8u) = o;
}

// ---------------- prep: h0 -> hb0 (bf16), gather x0, zero barriers ---------
__global__ __launch_bounds__(256) void prep_state_kernel(
    const float* __restrict__ h0a, const float* __restrict__ h0b,
    const int* __restrict__ batch_a, const int* __restrict__ batch_b,
    const float* __restrict__ emb,
    u16* __restrict__ hb0, u16* __restrict__ xb0, unsigned* __restrict__ bar) {
  unsigned i = blockIdx.x * 256u + threadIdx.x;
  unsigned r = i >> 10;
  unsigned k = i & 1023u;
  hb0[i] = f2bf((r < 128u) ? h0a[i] : h0b[i - 131072u]);
  int token = (r < 128u) ? batch_a[r] : batch_b[r - 128u];
  xb0[i] = f2bf(emb[(size_t)token * 1024u + k]);
  if (i < 128u) bar[i] = 0u;
}

// ---------------- persistent LSTM ----------------
// grid 256 = m(4) x nh(64). block 512 = 8 waves: kg(2) x wm(2) x wn(2).
// bar: per-group counter bar[m*32], generation bar[m*32+16] (128B apart).
__global__ __launch_bounds__(512, 2) void lstm_persist_kernel(
    const int* __restrict__ batch_a, const int* __restrict__ batch_b,
    const float* __restrict__ emb, const u16* __restrict__ Wf,
    const float* __restrict__ b_ih, const float* __restrict__ b_hh,
    const float* __restrict__ c0a, const float* __restrict__ c0b,
    u16* __restrict__ xb0, u16* __restrict__ xb1,
    u16* __restrict__ hb0, u16* __restrict__ hb1,
    unsigned* __restrict__ bar) {
  __shared__ u16 As[2][2][64][128];   // [kg][buf][row][k] 64 KB, swizzled rows
  __shared__ float Gs[2][64][68];     // [kg][row][gatecol] 34.8 KB partials

  const int tid = threadIdx.x;
  const int lane = tid & 63;
  const int w = tid >> 6;
  const int wm = (w >> 1) & 1, wn = w & 1, kg = w >> 2;
  const int m = blockIdx.x >> 6;
  const int nh = blockIdx.x & 63;

  // ---- staging map (kg half = 256 threads; 1 row, 32-elem chunk each) ----
  const int gtid = tid & 255;
  const int srow = gtid >> 2;          // 0..63
  const int scol = (gtid & 3) << 5;    // 0,32,64,96 (elems)
  const int wswz = (srow & 7) << 4;    // write swizzle (bytes)
  char* dstA0 = (char*)&As[kg][0][0][0] + srow * 256;
  char* dstA1 = (char*)&As[kg][1][0][0] + srow * 256;
  const size_t aOff = ((size_t)(m * 64 + srow) << 10) + scol;

  // ---- B fragment bases (fragment-ordered Wf; 512 elems per frag) ----
  const u16* wf0 = Wf + ((((size_t)(nh * 4 + wn * 2) * 64) + kg * 32) << 9) + lane * 8;
  const u16* wf1 = wf0 + (64 << 9);

  // ---- fragment read ids ----
  const int fr = lane & 15;
  const int fkb = (lane >> 4) << 4;    // bytes
  const int Ra0 = wm * 32 + fr;
  const int Ra1 = Ra0 + 16;
  const int rswz = (fr & 7) << 4;
  const char* A0 = (const char*)&As[kg][0][0][0];
  const char* A1 = (const char*)&As[kg][1][0][0];

  // ---- persistent cell state + bias in registers ----
  const int crow = tid >> 3;            // 0..63
  const int u0 = (tid & 7) << 1;        // unit pair
  const int R2 = m * 64 + crow;
  const int gj = nh * 16 + u0;
  float bias_r[4][2];
#pragma unroll
  for (int f = 0; f < 4; ++f) {
    bias_r[f][0] = b_ih[f * 1024 + gj] + b_hh[f * 1024 + gj];
    bias_r[f][1] = b_ih[f * 1024 + gj + 1] + b_hh[f * 1024 + gj + 1];
  }
  float creg[2];
  creg[0] = (R2 < 128) ? c0a[R2 * 1024 + gj] : c0b[(R2 - 128) * 1024 + gj];
  creg[1] = (R2 < 128) ? c0a[R2 * 1024 + gj + 1] : c0b[(R2 - 128) * 1024 + gj + 1];

  for (int t = 0; t < 128; ++t) {
    const u16* x_in = (t & 1) ? xb1 : xb0;
    u16* x_nx = (t & 1) ? xb0 : xb1;
    const u16* h_in = (t & 1) ? hb1 : hb0;
    u16* h_out = (t & 1) ? hb0 : hb1;

    // ---- issue x_{t+1} emb-gather loads early (hide under GEMM) ----
    float4 g0 = {0, 0, 0, 0}, g1 = {0, 0, 0, 0};
    const bool do_g = (t + 1 < 128) && (tid < 128);
    if (do_g) {
      int r = blockIdx.x;
      int token = (r < 128) ? batch_a[(t + 1) * 128 + r]
                            : batch_b[(t + 1) * 128 + (r - 128)];
      const float* es = emb + (size_t)token * 1024 + tid * 8;
      g0 = *(const float4*)es;
      g1 = *(const float4*)(es + 4);
    }

    const u16* aBase = (kg == 0 ? x_in : h_in) + aOff;

    f32x4 acc[2][2];
#pragma unroll
    for (int a_ = 0; a_ < 2; ++a_)
#pragma unroll
      for (int b_ = 0; b_ < 2; ++b_) acc[a_][b_] = (f32x4){0.f, 0.f, 0.f, 0.f};

    // preload it=0
    u16x8 ar[4];
    s16x8 brc[8], brn[8];
#pragma unroll
    for (int q = 0; q < 4; ++q) ar[q] = *(const u16x8*)(aBase + q * 8);
#pragma unroll
    for (int kcl = 0; kcl < 4; ++kcl) {
      brc[kcl * 2]     = *(const s16x8*)(wf0 + (kcl << 9));
      brc[kcl * 2 + 1] = *(const s16x8*)(wf1 + (kcl << 9));
    }

#pragma unroll
    for (int it = 0; it < 8; ++it) {
      {  // stage A tile (swizzled, bank-floor map)
        char* dst = (it & 1) ? dstA1 : dstA0;
#pragma unroll
        for (int q = 0; q < 4; ++q)
          *(u16x8*)(dst + ((scol * 2 + q * 16) ^ wswz)) = ar[q];
      }
      __syncthreads();
      if (it < 7) {  // prefetch next A chunk + next B frags
        const u16* an = aBase + (it + 1) * 128;
#pragma unroll
        for (int q = 0; q < 4; ++q) ar[q] = *(const u16x8*)(an + q * 8);
#pragma unroll
        for (int kcl = 0; kcl < 4; ++kcl) {
          brn[kcl * 2]     = *(const s16x8*)(wf0 + (((it + 1) * 4 + kcl) << 9));
          brn[kcl * 2 + 1] = *(const s16x8*)(wf1 + (((it + 1) * 4 + kcl) << 9));
        }
      }
      const char* ab = (it & 1) ? A1 : A0;
#pragma unroll
      for (int kcl = 0; kcl < 4; ++kcl) {
        s16x8 af0 = *(const s16x8*)(ab + Ra0 * 256 + ((kcl * 64 + fkb) ^ rswz));
        s16x8 af1 = *(const s16x8*)(ab + Ra1 * 256 + ((kcl * 64 + fkb) ^ rswz));
        acc[0][0] = __builtin_amdgcn_mfma_f32_16x16x32_bf16(af0, brc[kcl * 2],     acc[0][0], 0, 0, 0);
        acc[0][1] = __builtin_amdgcn_mfma_f32_16x16x32_bf16(af0, brc[kcl * 2 + 1], acc[0][1], 0, 0, 0);
        acc[1][0] = __builtin_amdgcn_mfma_f32_16x16x32_bf16(af1, brc[kcl * 2],     acc[1][0], 0, 0, 0);
        acc[1][1] = __builtin_amdgcn_mfma_f32_16x16x32_bf16(af1, brc[kcl * 2 + 1], acc[1][1], 0, 0, 0);
      }
      if (it < 7) {
#pragma unroll
        for (int q = 0; q < 8; ++q) brc[q] = brn[q];
      }
    }

    // ---- kg-partial gates to LDS (each kg its own plane), one barrier ----
#pragma unroll
    for (int a_ = 0; a_ < 2; ++a_)
#pragma unroll
      for (int b_ = 0; b_ < 2; ++b_)
#pragma unroll
        for (int r_ = 0; r_ < 4; ++r_)
          Gs[kg][wm * 32 + a_ * 16 + ((lane >> 4) << 2) + r_][wn * 32 + b_ * 16 + fr] =
              acc[a_][b_][r_];
    __syncthreads();

    // ---- fused cell update (c,bias in regs), packed h write ----
    {
      float hv[2];
#pragma unroll
      for (int uu = 0; uu < 2; ++uu) {
        int cix = u0 + uu;
        float iv = Gs[0][crow][cix]      + Gs[1][crow][cix]      + bias_r[0][uu];
        float fv = Gs[0][crow][16 + cix] + Gs[1][crow][16 + cix] + bias_r[1][uu];
        float gv = Gs[0][crow][32 + cix] + Gs[1][crow][32 + cix] + bias_r[2][uu];
        float ov = Gs[0][crow][48 + cix] + Gs[1][crow][48 + cix] + bias_r[3][uu];
        float si = 1.f / (1.f + __expf(-iv));
        float sf = 1.f / (1.f + __expf(-fv));
        float so = 1.f / (1.f + __expf(-ov));
        float cn = sf * creg[uu] + si * tanhf(gv);
        creg[uu] = cn;
        hv[uu] = so * tanhf(cn);
      }
      unsigned pk = (unsigned)f2bf(hv[0]) | ((unsigned)f2bf(hv[1]) << 16);
      *(unsigned*)(h_out + (size_t)R2 * 1024 + gj) = pk;
    }

    // ---- store pre-gathered x_{t+1} row ----
    if (do_g) {
      int r = blockIdx.x;
      u16x8 o;
      o[0] = f2bf(g0.x); o[1] = f2bf(g0.y); o[2] = f2bf(g0.z); o[3] = f2bf(g0.w);
      o[4] = f2bf(g1.x); o[5] = f2bf(g1.y); o[6] = f2bf(g1.z); o[7] = f2bf(g1.w);
      *(u16x8*)(x_nx + (size_t)r * 1024 + tid * 8) = o;
    }

    // ---- per-m-group barrier (64 blocks; groups are fully independent) ----
    __syncthreads();
    if (tid == 0) {
      __threadfence();                                   // release h/x stores
      unsigned a = __hip_atomic_fetch_add(&bar[m * 32], 1u, __ATOMIC_ACQ_REL,
                                          __HIP_MEMORY_SCOPE_AGENT);
      if ((a & 63u) == 63u)                              // last of 64 in group
        __hip_atomic_fetch_add(&bar[m * 32 + 16], 1u, __ATOMIC_ACQ_REL,
                               __HIP_MEMORY_SCOPE_AGENT);
      while (__hip_atomic_load(&bar[m * 32 + 16], __ATOMIC_ACQUIRE,
                               __HIP_MEMORY_SCOPE_AGENT) < (unsigned)(t + 1)) {
        __builtin_amdgcn_s_sleep(1);
      }
      __threadfence();                                   // acquire/invalidate
    }
    __syncthreads();
  }
}

// ---------------- finalize ----------------
__global__ __launch_bounds__(256) void finalize_kernel(const u16* __restrict__ h,
                                                       float* __restrict__ out) {
  int b = blockIdx.x;
  int tid = threadIdx.x;
  const u16* ha = h + (size_t)b * 1024;
  const u16* hb = h + (size_t)(b + 128) * 1024;
  float s = 0.f;
  for (int j = tid; j < 1024; j += 256) s += fabsf(bf2f(ha[j]) - bf2f(hb[j]));
  __shared__ float red[256];
  red[tid] = s;
  __syncthreads();
  for (int off = 128; off > 0; off >>= 1) {
    if (tid < off) red[tid] += red[tid + off];
    __syncthreads();
  }
  if (tid == 0) out[b] = expf(-red[0]);
}

extern "C" void kernel_launch(void* const* d_in, const int* in_sizes, int n_in,
                              void* d_out, int out_size, void* d_ws, size_t ws_size,
                              hipStream_t stream) {
  const int* batch_a = (const int*)d_in[0];
  const int* batch_b = (const int*)d_in[1];
  const float* h0_a = (const float*)d_in[2];
  const float* c0_a = (const float*)d_in[3];
  const float* h0_b = (const float*)d_in[4];
  const float* c0_b = (const float*)d_in[5];
  const float* emb  = (const float*)d_in[6];
  const float* w_ih = (const float*)d_in[7];
  const float* w_hh = (const float*)d_in[8];
  const float* b_ih = (const float*)d_in[9];
  const float* b_hh = (const float*)d_in[10];

  char* ws = (char*)d_ws;
  u16* Wf  = (u16*)(ws);                       // 16,777,216 B
  u16* xb0 = (u16*)(ws + 16777216);            //    524,288 B
  u16* xb1 = (u16*)(ws + 17301504);            //    524,288 B
  u16* hb0 = (u16*)(ws + 17825792);            //    524,288 B
  u16* hb1 = (u16*)(ws + 18350080);            //    524,288 B
  unsigned* bar = (unsigned*)(ws + 18874368);  //        512 B

  prep_wf_kernel<<<4096, 256, 0, stream>>>(w_ih, w_hh, Wf);
  prep_state_kernel<<<1024, 256, 0, stream>>>(h0_a, h0_b, batch_a, batch_b, emb,
                                              hb0, xb0, bar);

  void* args[] = {(void*)&batch_a, (void*)&batch_b, (void*)&emb, (void*)&Wf,
                  (void*)&b_ih, (void*)&b_hh, (void*)&c0_a, (void*)&c0_b,
                  (void*)&xb0, (void*)&xb1, (void*)&hb0, (void*)&hb1,
                  (void*)&bar};
  hipLaunchCooperativeKernel((void*)lstm_persist_kernel, dim3(256), dim3(512),
                             args, 0, stream);

  finalize_kernel<<<128, 256, 0, stream>>>(hb0, (float*)d_out);
}